// Round 5
// baseline (482.683 us; speedup 1.0000x reference)
//
#include <hip/hip_runtime.h>
#include <math.h>

// Planar normalizing flow, B=524288 rows, D=64, F=32.
// FOUR lanes per row, each lane owns a contiguous 16-element slice of z
// (4x f4 = 16 VGPRs of state). Rounds 1-4 showed one-thread-per-row (64
// floats of state) never stays in arch VGPRs: compiler parks it in AGPRs
// (VGPR_Count=40, occupancy 47%) and partially spills (WRITE 181MB vs 134
// ideal). Small per-lane state kills that entire failure mode.
// Dot product: f4 vector FMAs + 3 horizontal adds + 2 __shfl_xor stages.
// Params (w, uhat slices) are per-lane VMEM loads, 32KB total -> L1-hot;
// bs/wuh stay wave-uniform s_loads.

#define NF_D 64
#define NF_F 32

typedef float f4 __attribute__((ext_vector_type(4)));

// --- Step 1: precompute u_hat[F][D] and wuh[F] = w . u_hat ---------------
__global__ void nf_precompute(const float* __restrict__ us,
                              const float* __restrict__ ws,
                              float* __restrict__ uhat,
                              float* __restrict__ wuh) {
  int f = threadIdx.x;
  if (f >= NF_F) return;
  const float* u = us + f * NF_D;
  const float* w = ws + f * NF_D;
  float wu = 0.f, n2 = 0.f;
  for (int d = 0; d < NF_D; ++d) {
    wu = fmaf(u[d], w[d], wu);
    n2 = fmaf(w[d], w[d], n2);
  }
  float sp = fmaxf(wu, 0.f) + log1pf(expf(-fabsf(wu)));  // softplus
  float coef = (sp - 1.f - wu) / sqrtf(n2);   // u_hat = u + coef * w
  for (int d = 0; d < NF_D; ++d)
    uhat[f * NF_D + d] = fmaf(coef, w[d], u[d]);
  wuh[f] = fmaf(coef, n2, wu);                // w . u_hat
}

// tanh(x) = 1 - 2/(e^{2x}+1); exp2/rcp hardware approx; saturates to +-1.
__device__ __forceinline__ float fast_tanh(float x) {
  float e = __builtin_amdgcn_exp2f(x * 2.885390081777927f); // 2*log2(e)
  return 1.f - 2.f * __builtin_amdgcn_rcpf(e + 1.f);
}

// --- Step 2: main flow, 4 lanes per row ----------------------------------
__global__ __launch_bounds__(256) void nf_main(
    const float* __restrict__ x,
    const float* __restrict__ ws,
    const float* __restrict__ bs,
    const float* __restrict__ uhat,
    const float* __restrict__ wuh,
    float* __restrict__ out_z,
    float* __restrict__ out_ld,
    int B) {
  int tid = blockIdx.x * blockDim.x + threadIdx.x;
  int row = tid >> 2;
  int l   = tid & 3;                 // lane-in-row, owns elements [16l,16l+16)
  if (row >= B) return;

  const f4* __restrict__ xv =
      reinterpret_cast<const f4*>(x + (size_t)row * NF_D + l * 16);
  f4 z0 = xv[0], z1 = xv[1], z2 = xv[2], z3 = xv[3];

  float ldp = 1.f;                   // product of (1 + h' * w.u_hat)
  #pragma unroll 2
  for (int f = 0; f < NF_F; ++f) {
    const f4* __restrict__ wq =
        reinterpret_cast<const f4*>(ws + f * NF_D + l * 16);
    const f4* __restrict__ uq =
        reinterpret_cast<const f4*>(uhat + f * NF_D + l * 16);
    f4 w0 = wq[0], w1 = wq[1], w2 = wq[2], w3 = wq[3];

    f4 acc = z0 * w0;
    acc += z1 * w1;
    acc += z2 * w2;
    acc += z3 * w3;                  // v_pk_fma_f32 pairs
    float s = (acc.x + acc.y) + (acc.z + acc.w);
    s += __shfl_xor(s, 1);           // reduce across the 4-lane group
    s += __shfl_xor(s, 2);
    float lin = s + bs[f];           // bs[f]: wave-uniform s_load
    float h = fast_tanh(lin);

    f4 u0 = uq[0], u1 = uq[1], u2 = uq[2], u3 = uq[3];
    z0 += u0 * h; z1 += u1 * h; z2 += u2 * h; z3 += u3 * h;

    float hp = fmaf(-h, h, 1.f);     // 1 - h^2
    ldp *= fmaf(hp, wuh[f], 1.f);    // 1 + h' * (w.u_hat)
  }

  f4* __restrict__ ov =
      reinterpret_cast<f4*>(out_z + (size_t)row * NF_D + l * 16);
  ov[0] = z0; ov[1] = z1; ov[2] = z2; ov[3] = z3;
  if (l == 0)                        // one logdet per row
    out_ld[row] = __builtin_amdgcn_logf(fabsf(ldp)) * 0.6931471805599453f;
}

extern "C" void kernel_launch(void* const* d_in, const int* in_sizes, int n_in,
                              void* d_out, int out_size, void* d_ws, size_t ws_size,
                              hipStream_t stream) {
  const float* x    = (const float*)d_in[0];
  const float* us   = (const float*)d_in[1];
  const float* ws_p = (const float*)d_in[2];
  const float* bs   = (const float*)d_in[3];
  const int B = in_sizes[0] / NF_D;

  float* uhat = (float*)d_ws;            // F*D floats
  float* wuh  = uhat + NF_F * NF_D;      // F floats
  float* out  = (float*)d_out;           // z [B*D] then sum_log_det [B]

  nf_precompute<<<1, 64, 0, stream>>>(us, ws_p, uhat, wuh);
  const int block = 256;
  const long long threads = (long long)B * 4;
  const int grid = (int)((threads + block - 1) / block);
  nf_main<<<grid, block, 0, stream>>>(x, ws_p, bs, uhat, wuh,
                                      out, out + (size_t)B * NF_D, B);
}

// Round 6
// 135.592 us; speedup vs baseline: 3.5598x; 3.5598x over previous
//
#include <hip/hip_runtime.h>
#include <math.h>

// Planar normalizing flow, B=524288 rows, D=64, F=32.
// Key algebraic restructure: z_f = x + sum_{g<f} u_g h_g, so
//   lin_f = x.w_f + b_f + sum_{g<f} (u_g.w_f) h_g.
// Precompute G[f][g] = u_hat_g . w_f (triangular, zero-padded) and W^T.
// Main kernel per row runs three SMALL-STATE phases:
//   A: c[f] = x.w_f        (stream x, state = c[32])
//   B: h[f] recurrence     (in-place over c, state = 32 floats)
//   C: z = x + U_hat^T h   (stream chunks of 8, state = h[32] + acc[8])
// All params are wave-uniform -> scalar s_loads. This avoids both observed
// failure modes: 64-float state carried through the serial loop (rounds 1-4:
// AGPR parking / scratch spill) and per-lane VMEM param loads (round 5:
// L1-port bound, 12% VALUBusy at 88% occupancy).

#define NF_D 64
#define NF_F 32

typedef float f4 __attribute__((ext_vector_type(4)));

// ws layout (floats): uhat[32][64] | wuh[32] | wt[64][32] | Gt[32][32]
#define WS_UHAT 0
#define WS_WUH  (NF_F * NF_D)
#define WS_WT   (WS_WUH + NF_F)
#define WS_GT   (WS_WT + NF_D * NF_F)

// --- precompute: u_hat, wuh, W^T, G -------------------------------------
__global__ void nf_precompute(const float* __restrict__ us,
                              const float* __restrict__ ws,
                              float* __restrict__ wsbuf) {
  __shared__ float s_u[NF_F][NF_D];
  float* uhat = wsbuf + WS_UHAT;
  float* wuh  = wsbuf + WS_WUH;
  float* wt   = wsbuf + WS_WT;
  float* Gt   = wsbuf + WS_GT;
  int t = threadIdx.x;
  if (t < NF_F) {
    const float* u = us + t * NF_D;
    const float* w = ws + t * NF_D;
    float wu = 0.f, n2 = 0.f;
    for (int d = 0; d < NF_D; ++d) {
      wu = fmaf(u[d], w[d], wu);
      n2 = fmaf(w[d], w[d], n2);
    }
    float sp = fmaxf(wu, 0.f) + log1pf(expf(-fabsf(wu)));  // softplus
    float coef = (sp - 1.f - wu) / sqrtf(n2);
    for (int d = 0; d < NF_D; ++d) {
      float uh = fmaf(coef, w[d], u[d]);
      s_u[t][d] = uh;
      uhat[t * NF_D + d] = uh;
    }
    wuh[t] = fmaf(coef, n2, wu);         // w_t . u_hat_t
  }
  __syncthreads();
  for (int i = t; i < NF_D * NF_F; i += 256) {   // wt[d][f] = ws[f][d]
    int d = i / NF_F, f = i % NF_F;
    wt[i] = ws[f * NF_D + d];
  }
  for (int i = t; i < NF_F * NF_F; i += 256) {   // Gt[f][g] = u_hat_g . w_f
    int f = i / NF_F, g = i % NF_F;
    float s = 0.f;
    if (g < f) {
      const float* w = ws + f * NF_D;
      for (int d = 0; d < NF_D; ++d) s = fmaf(s_u[g][d], w[d], s);
    }
    Gt[i] = s;                                   // zero-padded for g >= f
  }
}

// tanh(x) = 1 - 2/(e^{2x}+1); hardware exp2/rcp; saturates to +-1.
__device__ __forceinline__ float fast_tanh(float x) {
  float e = __builtin_amdgcn_exp2f(x * 2.885390081777927f); // 2*log2(e)
  return 1.f - 2.f * __builtin_amdgcn_rcpf(e + 1.f);
}

// --- main: one thread per row, three small-state phases ------------------
__global__ __launch_bounds__(256) void nf_main(
    const float* __restrict__ x,
    const float* __restrict__ bs,
    const float* __restrict__ wsbuf,
    float* __restrict__ out_z,
    float* __restrict__ out_ld,
    int B) {
  const float* __restrict__ uhat = wsbuf + WS_UHAT;
  const float* __restrict__ wuh  = wsbuf + WS_WUH;
  const float* __restrict__ wt   = wsbuf + WS_WT;
  const float* __restrict__ Gt   = wsbuf + WS_GT;

  int row = blockIdx.x * blockDim.x + threadIdx.x;
  if (row >= B) return;
  const f4* __restrict__ xv = reinterpret_cast<const f4*>(x + (size_t)row * NF_D);

  // ---- Phase A: c[f] = x . w_f (via transposed wt, uniform s_loads) ----
  f4 c4[NF_F / 4];
  #pragma unroll
  for (int q = 0; q < NF_F / 4; ++q) c4[q] = (f4)(0.f);
  #pragma unroll 2
  for (int dc = 0; dc < NF_D / 4; ++dc) {
    f4 xd = xv[dc];
    #pragma unroll
    for (int j = 0; j < 4; ++j) {
      const f4* __restrict__ wr =
          reinterpret_cast<const f4*>(wt + (dc * 4 + j) * NF_F);
      float xs = xd[j];
      #pragma unroll
      for (int q = 0; q < NF_F / 4; ++q)
        c4[q] += wr[q] * xs;             // v_pk_fma_f32, SGPR w operand
    }
  }

  // ---- Phase B: recurrence, h[f] overwrites c[f] in place --------------
  float ldp = 1.f;
  #pragma unroll
  for (int f = 0; f < NF_F; ++f) {
    const f4* __restrict__ g4 = reinterpret_cast<const f4*>(Gt + f * NF_F);
    f4 a = (f4)(0.f);
    #pragma unroll
    for (int q = 0; q < (f + 3) / 4; ++q)   // zero-padded triangular
      a += g4[q] * c4[q];                   // slots >= f hit Gt zeros
    float s = c4[f / 4][f % 4] + bs[f] + ((a.x + a.y) + (a.z + a.w));
    float hf = fast_tanh(s);
    float hp = fmaf(-hf, hf, 1.f);          // 1 - h^2
    ldp *= fmaf(hp, wuh[f], 1.f);           // 1 + h'*(w.u_hat)
    c4[f / 4][f % 4] = hf;                  // h[f] replaces c[f]
  }

  // ---- Phase C: z = x + U_hat^T h, streamed 8 floats at a time ---------
  f4* __restrict__ ov = reinterpret_cast<f4*>(out_z + (size_t)row * NF_D);
  #pragma unroll 2
  for (int dc = 0; dc < NF_D / 8; ++dc) {
    f4 a0 = xv[2 * dc], a1 = xv[2 * dc + 1];   // x re-read: LLC-resident
    #pragma unroll
    for (int f = 0; f < NF_F; ++f) {
      const f4* __restrict__ uq =
          reinterpret_cast<const f4*>(uhat + f * NF_D + dc * 8);
      float hf = c4[f / 4][f % 4];
      a0 += uq[0] * hf;                    // pk_fma, SGPR uhat operand
      a1 += uq[1] * hf;
    }
    ov[2 * dc] = a0;
    ov[2 * dc + 1] = a1;
  }
  out_ld[row] = __builtin_amdgcn_logf(fabsf(ldp)) * 0.6931471805599453f;
}

extern "C" void kernel_launch(void* const* d_in, const int* in_sizes, int n_in,
                              void* d_out, int out_size, void* d_ws, size_t ws_size,
                              hipStream_t stream) {
  const float* x    = (const float*)d_in[0];
  const float* us   = (const float*)d_in[1];
  const float* ws_p = (const float*)d_in[2];
  const float* bs   = (const float*)d_in[3];
  const int B = in_sizes[0] / NF_D;

  float* wsbuf = (float*)d_ws;   // 5152 floats ~ 20.6 KB
  float* out   = (float*)d_out;  // z [B*D] then sum_log_det [B]

  nf_precompute<<<1, 256, 0, stream>>>(us, ws_p, wsbuf);
  const int block = 256;
  const int grid = (B + block - 1) / block;
  nf_main<<<grid, block, 0, stream>>>(x, bs, wsbuf,
                                      out, out + (size_t)B * NF_D, B);
}